// Round 3
// baseline (59.359 us; speedup 1.0000x reference)
//
#include <hip/hip_runtime.h>
#include <hip/hip_cooperative_groups.h>

namespace cg = cooperative_groups;

// x: (16,1,2048,2048) f32
// out = iv (16,2032) f32 | dv (16,2017) f32 | band (16,2015) f32(0/1), concat flat.

#define NN    2048
#define KW    17
#define LL    2032
#define DS    8
#define LD    2017
#define LB    2015
#define BATCH 16
#define TILE  64
#define NTILES ((LL + TILE - 1) / TILE)   // 32
#define TROWS (TILE + KW - 1)             // 80
#define TCOLS (TILE + KW - 1)             // 80

// ---------------------------------------------------------------------------
// Single cooperative kernel, 512 blocks x 256 threads (2 blocks/CU).
// Phase 1 (per block = one (tile,b)):
//   - stage 80x80 f32 tile (coalesced float4)
//   - vertical 17-sums in LDS, then diagonal horizontal 17-sums -> S[b,i]
//   - f64 per-block partial sum of S  (for the global mean)
// grid.sync()
// Phase 2 (same block finishes its own 64-wide slice):
//   - every block redundantly reduces the 512 partials (4 KB, L2-hit)
//   - iv = log2f(S*c) for local region [i0, i0+96) (neighbor S from L2)
//   - dv for [i0, i0+66), band for [i0, i0+64), write own slices
// ---------------------------------------------------------------------------
__global__ __launch_bounds__(256) void kFused(const float* __restrict__ x,
                                              float* __restrict__ S,
                                              double* __restrict__ part,
                                              float* __restrict__ out) {
    __shared__ float  tile[TROWS * TCOLS];   // 25.6 KB
    __shared__ float  V[TILE * TCOLS];       // 20.5 KB
    __shared__ double wred[4];
    __shared__ float  ivloc[96];
    __shared__ float  dvloc[68];

    const int bid = blockIdx.x;
    const int tl  = bid & (NTILES - 1);      // NTILES = 32
    const int b   = bid >> 5;
    const int i0  = tl * TILE;
    const int nout = (LL - i0 < TILE) ? (LL - i0) : TILE;   // 64 or 48
    const int tid = threadIdx.x;
    const float* xb = x + (size_t)b * NN * NN;

    // ---- phase 1: stage tile ----
    for (int f = tid; f < TROWS * (TCOLS / 4); f += 256) {    // 80*20
        int r  = f / (TCOLS / 4);
        int c4 = f - r * (TCOLS / 4);
        int gr = i0 + r;
        int gc = i0 + c4 * 4;
        if (gr < NN && gc + 3 < NN) {
            float4 v = *reinterpret_cast<const float4*>(xb + (size_t)gr * NN + gc);
            *reinterpret_cast<float4*>(&tile[r * TCOLS + c4 * 4]) = v;
        }
    }
    __syncthreads();

    // vertical 17-sums (exact, two accumulators)
    const int ncols = nout + KW - 1;
    for (int p = tid; p < TILE * TCOLS; p += 256) {
        int j = p / TCOLS;
        int c = p - j * TCOLS;
        if (j < nout && c < ncols) {
            float a0 = 0.f, a1 = 0.f;
            #pragma unroll
            for (int dr = 0; dr < 16; dr += 2) {
                a0 += tile[(j + dr) * TCOLS + c];
                a1 += tile[(j + dr + 1) * TCOLS + c];
            }
            a0 += tile[(j + 16) * TCOLS + c];
            V[j * TCOLS + c] = a0 + a1;
        }
    }
    __syncthreads();

    // diagonal horizontal 17-sums (wave 0); stride-81 LDS reads: 2-way max
    double ps = 0.0;
    if (tid < 64) {
        int j = tid;
        if (j < nout) {
            float s0 = 0.f, s1 = 0.f;
            #pragma unroll
            for (int dc = 0; dc < 16; dc += 2) {
                s0 += V[j * TCOLS + j + dc];
                s1 += V[j * TCOLS + j + dc + 1];
            }
            s0 += V[j * TCOLS + j + 16];
            float s = s0 + s1;
            S[b * LL + i0 + j] = s;
            ps = (double)s;
        }
        #pragma unroll
        for (int off = 32; off > 0; off >>= 1)
            ps += __shfl_down(ps, off, 64);
        if (tid == 0) part[b * NTILES + tl] = ps;
    }

    // ---- all S + partials visible device-wide after this ----
    cg::this_grid().sync();

    // ---- phase 2: redundant global-mean reduce (512 f64, L2-hit) ----
    double p = 0.0;
    for (int t = tid; t < BATCH * NTILES; t += 256) p += part[t];
    #pragma unroll
    for (int off = 32; off > 0; off >>= 1) p += __shfl_down(p, off, 64);
    if ((tid & 63) == 0) wred[tid >> 6] = p;
    __syncthreads();
    const double total = wred[0] + wred[1] + wred[2] + wred[3];
    // iv = log2(S * (B*LL)/total); the global-mean factor cancels in dv.
    const float c = (float)((double)(BATCH * LL) / total);

    // iv for local region [i0, i0+96) clamped to LL; write own [i0, i0+64)
    const int nreg = (LL - i0 < 96) ? (LL - i0) : 96;
    for (int i = tid; i < nreg; i += 256) {
        float iv = log2f(S[b * LL + i0 + i] * c);
        ivloc[i] = iv;
        if (i < TILE) out[b * LL + i0 + i] = iv;
    }
    __syncthreads();

    // dv for [i0, i0+68) clamped to LD; write own [i0, i0+64)
    float* out_dv = out + BATCH * LL;
    int ndv = LD - i0; if (ndv > 68) ndv = 68; if (ndv < 0) ndv = 0;
    for (int j = tid; j < ndv; j += 256) {
        float t0 = 0.f, t1 = 0.f, b0 = 0.f, b1 = 0.f;
        #pragma unroll
        for (int t = 0; t < 8; t += 2) {
            b0 += ivloc[j + t];
            b1 += ivloc[j + t + 1];
            t0 += ivloc[j + DS + t];
            t1 += ivloc[j + DS + t + 1];
        }
        float dv = ((t0 + t1) - (b0 + b1)) * 0.125f;
        dvloc[j] = dv;
        if (j < TILE) out_dv[b * LD + i0 + j] = dv;
    }
    __syncthreads();

    // band for own [i0, i0+64) clamped to LB
    float* out_band = out + BATCH * (LL + LD);
    int nband = LB - i0; if (nband > TILE) nband = TILE; if (nband < 0) nband = 0;
    for (int j = tid; j < nband; j += 256) {
        out_band[b * LB + i0 + j] = (dvloc[j] < 0.f && dvloc[j + 2] > 0.f) ? 1.0f : 0.0f;
    }
}

extern "C" void kernel_launch(void* const* d_in, const int* in_sizes, int n_in,
                              void* d_out, int out_size, void* d_ws, size_t ws_size,
                              hipStream_t stream) {
    const float* x = (const float*)d_in[0];
    float* out = (float*)d_out;

    // ws: S[16*2032] f32 (130048 B), pad to 16, then part[16*32] f64
    float*  S    = (float*)d_ws;
    double* part = (double*)((char*)d_ws + ((BATCH * LL * sizeof(float) + 15) & ~15));

    void* args[] = { (void*)&x, (void*)&S, (void*)&part, (void*)&out };
    hipLaunchCooperativeKernel((const void*)kFused,
                               dim3(BATCH * NTILES), dim3(256),
                               args, 0, stream);
}

// Round 5
// 13.030 us; speedup vs baseline: 4.5556x; 4.5556x over previous
//
#include <hip/hip_runtime.h>

// x: (16,1,2048,2048) f32
// out = iv (16,2032) f32 | dv (16,2017) f32 | band (16,2015) f32(0/1), concat flat.

#define NN    2048
#define KW    17
#define LL    2032
#define DS    8
#define LD    2017
#define LB    2015
#define BATCH 16
#define TILE  64
#define NTILES ((LL + TILE - 1) / TILE)   // 32
#define TROWS (TILE + KW - 1)             // 80
#define TCOLS (TILE + KW - 1)             // 80
#define VPAD  19                          // Vb row stride (gcd(19,32)=1 -> 2-way max)
#define NSLICE 8
#define SW    254                         // 8*254 = 2032

// ---------------------------------------------------------------------------
// Kernel A: per (tile,b) block of 256 threads.
//  - stage 80x80 f32 tile (coalesced float4)
//  - BANDED vertical 17-sums: only the 64x17 entries the diagonal pass reads
//    (same accumulation order as R2 -> bit-identical S)
//  - diagonal horizontal 17-sums -> S[b,i]; f64 per-block partial for gmean
// ---------------------------------------------------------------------------
__global__ __launch_bounds__(256) void kA(const float* __restrict__ x,
                                          float* __restrict__ S,
                                          double* __restrict__ part) {
    __shared__ float tile[TROWS * TCOLS];   // 25.6 KB
    __shared__ float Vb[TILE * VPAD];       // 4.8 KB

    const int tl  = blockIdx.x;
    const int b   = blockIdx.y;
    const int i0  = tl * TILE;
    const int nout = (LL - i0 < TILE) ? (LL - i0) : TILE;   // 64 or 48
    const int tid = threadIdx.x;
    const float* xb = x + (size_t)b * NN * NN;

    // stage: rows [i0,i0+80) x cols [i0,i0+80), clamped at 2048
    for (int f = tid; f < TROWS * (TCOLS / 4); f += 256) {    // 80*20 = 1600
        int r  = f / (TCOLS / 4);
        int c4 = f - r * (TCOLS / 4);
        int gr = i0 + r;
        int gc = i0 + c4 * 4;
        if (gr < NN && gc + 3 < NN) {
            float4 v = *reinterpret_cast<const float4*>(xb + (size_t)gr * NN + gc);
            *reinterpret_cast<float4*>(&tile[r * TCOLS + c4 * 4]) = v;
        }
    }
    __syncthreads();

    // banded vertical 17-sums: Vb[j][d] = sum_{dr<17} tile[j+dr][j+d], d<17
    for (int p = tid; p < nout * KW; p += 256) {              // <= 1088
        int j = p / KW;
        int d = p - j * KW;
        int c = j + d;
        float a0 = 0.f, a1 = 0.f;
        #pragma unroll
        for (int dr = 0; dr < 16; dr += 2) {
            a0 += tile[(j + dr) * TCOLS + c];
            a1 += tile[(j + dr + 1) * TCOLS + c];
        }
        a0 += tile[(j + 16) * TCOLS + c];
        Vb[j * VPAD + d] = a0 + a1;
    }
    __syncthreads();

    // diagonal horizontal 17-sums (wave 0)
    double ps = 0.0;
    if (tid < 64) {
        int j = tid;
        if (j < nout) {
            float s0 = 0.f, s1 = 0.f;
            #pragma unroll
            for (int dc = 0; dc < 16; dc += 2) {
                s0 += Vb[j * VPAD + dc];
                s1 += Vb[j * VPAD + dc + 1];
            }
            s0 += Vb[j * VPAD + 16];
            float s = s0 + s1;
            S[b * LL + i0 + j] = s;
            ps = (double)s;
        }
        #pragma unroll
        for (int off = 32; off > 0; off >>= 1)
            ps += __shfl_down(ps, off, 64);
        if (tid == 0) part[b * NTILES + tl] = ps;
    }
}

// ---------------------------------------------------------------------------
// Kernel B: 128 blocks (16 images x 8 slices) x 256 threads.
//  phase 0: every block redundantly reduces the 512 f64 partials (L2-hit)
//  phase 1: iv = log2f(S*c) for slice + 17 halo (dv halo j=SW+1 reads
//           iv[j+15] -> local index SW+16 -> need SW+17 entries!)
//  phase 2: dv for slice + 2 halo
//  phase 3: band for slice
// ---------------------------------------------------------------------------
__global__ __launch_bounds__(256) void kB(const float* __restrict__ S,
                                          const double* __restrict__ part,
                                          float* __restrict__ out) {
    __shared__ double wred[4];
    __shared__ float  ivloc[SW + 18];   // 272, fill 271
    __shared__ float  dvloc[SW + 2];    // 256

    const int b   = blockIdx.x >> 3;
    const int sl  = blockIdx.x & 7;
    const int i0  = sl * SW;
    const int tid = threadIdx.x;

    // phase 0: global mean
    double p = 0.0;
    for (int t = tid; t < BATCH * NTILES; t += 256) p += part[t];
    #pragma unroll
    for (int off = 32; off > 0; off >>= 1) p += __shfl_down(p, off, 64);
    if ((tid & 63) == 0) wred[tid >> 6] = p;
    __syncthreads();
    const double total = wred[0] + wred[1] + wred[2] + wred[3];
    // iv = log2(S * (B*LL)/total); gmean factor cancels in dv.
    const float c = (float)((double)(BATCH * LL) / total);

    // phase 1: iv for [i0, i0+SW+17) clamped; write own [i0, i0+SW)
    const int nreg = (LL - i0 < SW + 17) ? (LL - i0) : (SW + 17);
    for (int i = tid; i < nreg; i += 256) {
        float iv = log2f(S[b * LL + i0 + i] * c);
        ivloc[i] = iv;
        if (i < SW) out[b * LL + i0 + i] = iv;
    }
    __syncthreads();

    // phase 2: dv for [i0, i0+SW+2) clamped to LD; write own [i0, i0+SW)
    float* out_dv = out + BATCH * LL;
    int ndv = LD - i0; if (ndv > SW + 2) ndv = SW + 2; if (ndv < 0) ndv = 0;
    for (int j = tid; j < ndv; j += 256) {
        float t0 = 0.f, t1 = 0.f, b0 = 0.f, b1 = 0.f;
        #pragma unroll
        for (int t = 0; t < 8; t += 2) {
            b0 += ivloc[j + t];
            b1 += ivloc[j + t + 1];
            t0 += ivloc[j + DS + t];
            t1 += ivloc[j + DS + t + 1];
        }
        float dv = ((t0 + t1) - (b0 + b1)) * 0.125f;
        dvloc[j] = dv;
        if (j < SW) out_dv[b * LD + i0 + j] = dv;
    }
    __syncthreads();

    // phase 3: band for own [i0, i0+SW) clamped to LB
    float* out_band = out + BATCH * (LL + LD);
    int nband = LB - i0; if (nband > SW) nband = SW; if (nband < 0) nband = 0;
    for (int j = tid; j < nband; j += 256) {
        out_band[b * LB + i0 + j] = (dvloc[j] < 0.f && dvloc[j + 2] > 0.f) ? 1.0f : 0.0f;
    }
}

extern "C" void kernel_launch(void* const* d_in, const int* in_sizes, int n_in,
                              void* d_out, int out_size, void* d_ws, size_t ws_size,
                              hipStream_t stream) {
    const float* x = (const float*)d_in[0];
    float* out = (float*)d_out;

    // ws: S[16*2032] f32 (130048 B), pad to 16, then part[16*32] f64
    float*  S    = (float*)d_ws;
    double* part = (double*)((char*)d_ws + ((BATCH * LL * sizeof(float) + 15) & ~15));

    dim3 gA(NTILES, BATCH);
    kA<<<gA, 256, 0, stream>>>(x, S, part);
    kB<<<NSLICE * BATCH, 256, 0, stream>>>(S, part, out);
}